// Round 11
// baseline (559.556 us; speedup 1.0000x reference)
//
#include <hip/hip_runtime.h>
#include <hip/hip_bf16.h>

#define NN 50000
#define EE 800000
#define FF 128
#define HH 256
#define GG 512
#define TT 5

typedef __attribute__((ext_vector_type(8))) short bf16x8_t;
typedef __attribute__((ext_vector_type(4))) float f32x4_t;
typedef __attribute__((ext_vector_type(2))) float f32x2_t;

__device__ __forceinline__ ushort f2b(float f) {
    union { float f; uint u; } c; c.f = f;
    uint u = c.u;
    u += 0x7fffu + ((u >> 16) & 1u);
    return (ushort)(u >> 16);
}
__device__ __forceinline__ float b2f(ushort h) {
    union { uint u; float f; } c; c.u = ((uint)h) << 16;
    return c.f;
}
__device__ __forceinline__ f32x2_t b2f2(uint q) {
    union { uint u; float f; } lo, hi;
    lo.u = q << 16; hi.u = q & 0xffff0000u;
    return (f32x2_t){lo.f, hi.f};
}
__device__ __forceinline__ uint pack2(float a, float b) {
    return (uint)f2b(a) | ((uint)f2b(b) << 16);
}

// ---------------------------------------------------------------------------
// Preprocessing
// ---------------------------------------------------------------------------
__global__ __launch_bounds__(256) void blocksum_kernel(const int* __restrict__ cnt,
                                                       int* __restrict__ bsum, int n) {
    __shared__ int sm[256];
    int i = blockIdx.x * 256 + threadIdx.x;
    sm[threadIdx.x] = (i < n) ? cnt[i] : 0;
    __syncthreads();
    for (int s = 128; s > 0; s >>= 1) {
        if ((int)threadIdx.x < s) sm[threadIdx.x] += sm[threadIdx.x + s];
        __syncthreads();
    }
    if (threadIdx.x == 0) bsum[blockIdx.x] = sm[0];
}

__global__ __launch_bounds__(256) void scanb_kernel(const int* __restrict__ bsum,
                                                    int* __restrict__ boff, int nb) {
    __shared__ int sm[256];
    int v = ((int)threadIdx.x < nb) ? bsum[threadIdx.x] : 0;
    sm[threadIdx.x] = v;
    __syncthreads();
    for (int off = 1; off < 256; off <<= 1) {
        int t = (threadIdx.x >= (unsigned)off) ? sm[threadIdx.x - off] : 0;
        __syncthreads();
        sm[threadIdx.x] += t;
        __syncthreads();
    }
    if ((int)threadIdx.x < nb) boff[threadIdx.x] = sm[threadIdx.x] - v;
}

__global__ __launch_bounds__(256) void rowptr_kernel(const int* __restrict__ cnt,
                                                     const int* __restrict__ boff,
                                                     int* __restrict__ row_ptr,
                                                     int* __restrict__ cursor,
                                                     float* __restrict__ dinv,
                                                     float* __restrict__ selfnorm, int n) {
    __shared__ int sm[256];
    int i = blockIdx.x * 256 + threadIdx.x;
    int v = (i < n) ? cnt[i] : 0;
    sm[threadIdx.x] = v;
    __syncthreads();
    for (int off = 1; off < 256; off <<= 1) {
        int t = (threadIdx.x >= (unsigned)off) ? sm[threadIdx.x - off] : 0;
        __syncthreads();
        sm[threadIdx.x] += t;
        __syncthreads();
    }
    int excl = boff[blockIdx.x] + sm[threadIdx.x] - v;
    if (i < n) {
        row_ptr[i] = excl;
        cursor[i] = 0;
        float dv = 1.0f / sqrtf((float)(v + 1));
        dinv[i] = dv;
        selfnorm[i] = dv * dv;
    }
    if (i == n - 1) row_ptr[n] = excl + v;
}

__global__ void scatter_kernel(const int* __restrict__ src, const int* __restrict__ dst,
                               const int* __restrict__ row_ptr, int* __restrict__ cursor,
                               uint2* __restrict__ meta,
                               const float* __restrict__ dinv, int e) {
    int t = blockIdx.x * blockDim.x + threadIdx.x;
    if (t >= e) return;
    int s = src[t], d = dst[t];
    int pos = row_ptr[d] + atomicAdd(&cursor[d], 1);
    uint2 m;
    m.x = (uint)s;
    m.y = __float_as_uint(dinv[s] * dinv[d]);
    meta[pos] = m;
}

// Fused: count | bp | wt casts | cvtx  (all independent; atomics into cnt)
#define CNTB ((EE + 255) / 256)
__global__ __launch_bounds__(256) void prep_kernel(const int* __restrict__ edst,
                                                   int* __restrict__ cnt,
                                                   const int* __restrict__ batch,
                                                   int* __restrict__ bp,
                                                   const float* __restrict__ W0,
                                                   const float* __restrict__ W1,
                                                   const float* __restrict__ W2,
                                                   const float* __restrict__ W3,
                                                   ushort* __restrict__ Wt0,
                                                   ushort* __restrict__ Wt1,
                                                   ushort* __restrict__ Wt2,
                                                   ushort* __restrict__ Wt3,
                                                   const float* __restrict__ x,
                                                   ushort* __restrict__ xb) {
    int b = blockIdx.x;
    if (b < CNTB) {
        int t = b * 256 + threadIdx.x;
        if (t < EE) atomicAdd(&cnt[edst[t]], 1);
    } else if (b < CNTB + 3) {
        int t = (b - CNTB) * 256 + threadIdx.x;
        if (t > GG) return;
        int lo = 0, hi = NN;
        while (lo < hi) {
            int mid = (lo + hi) >> 1;
            if (batch[mid] < t) lo = mid + 1; else hi = mid;
        }
        bp[t] = lo;
    } else if (b < CNTB + 3 + FF + 3 * HH) {
        int wb = b - CNTB - 3;
        const float* W; ushort* Wt; int K, kb;
        if (wb < FF)             { W = W0; Wt = Wt0; K = FF; kb = wb; }
        else if (wb < FF + HH)   { W = W1; Wt = Wt1; K = HH; kb = wb - FF; }
        else if (wb < FF + 2*HH) { W = W2; Wt = Wt2; K = HH; kb = wb - FF - HH; }
        else                     { W = W3; Wt = Wt3; K = HH; kb = wb - FF - 2*HH; }
        int n = threadIdx.x;
        Wt[(size_t)n * K + kb] = f2b(W[(size_t)kb * 256 + n]);
    } else {
        int i = (b - CNTB - 3 - FF - 3 * HH) * 256 + threadIdx.x;
        if (i >= NN * FF / 4) return;
        float4 v = ((const float4*)x)[i];
        ushort4 o;
        o.x = f2b(v.x); o.y = f2b(v.y); o.z = f2b(v.z); o.w = f2b(v.w);
        ((ushort4*)xb)[i] = o;
    }
}

// ---------------------------------------------------------------------------
// Aggregation v6 (unchanged — at structural floor: per-XCD misses ~= compulsory)
// ---------------------------------------------------------------------------
template<int C>
__global__ __launch_bounds__(256) void agg_kernel(const ushort* __restrict__ H,
                                                  const int* __restrict__ row_ptr,
                                                  const uint2* __restrict__ meta,
                                                  const float* __restrict__ selfnorm,
                                                  ushort* __restrict__ out) {
    constexpr int UPL = C / 128;
    constexpr int EPH = 8;
    constexpr int G   = 2 * EPH;
    int wave = threadIdx.x >> 6;
    int lane = threadIdx.x & 63;
    int h = lane >> 5;
    int cl = lane & 31;
    int colhalf = blockIdx.x & 1;
    int i = (blockIdx.x >> 1) * 4 + wave;
    if (i >= NN) return;

    const int coff = colhalf * (C / 4) + cl * UPL;

    f32x2_t acc2[UPL];
    #pragma unroll
    for (int k = 0; k < UPL; k++) acc2[k] = (f32x2_t){0.f, 0.f};

    const uint* rowbase = (const uint*)H;
    if (h == 0) {
        float sn = selfnorm[i];
        const uint* p = rowbase + (size_t)i * (C / 2) + coff;
        #pragma unroll
        for (int u = 0; u < UPL; u++) {
            f32x2_t v = b2f2(p[u]);
            acc2[u].x = sn * v.x;
            acc2[u].y = sn * v.y;
        }
    }

    int beg = row_ptr[i], end = row_ptr[i + 1];
    for (int base = beg; base < end; base += 64) {
        int t = base + lane;
        uint2 mt;
        if (t < end) mt = meta[t]; else { mt.x = 0u; mt.y = 0u; }
        int m = end - base; if (m > 64) m = 64;
        int full = m / G;
        for (int jj = 0; jj < full; jj++) {
            int   s[EPH];
            float w[EPH];
            #pragma unroll
            for (int u = 0; u < EPH; u++) {
                int e = G * jj + 2 * u + h;
                s[u] = __shfl((int)mt.x, e);
                w[u] = __uint_as_float((uint)__shfl((int)mt.y, e));
            }
            if constexpr (UPL == 2) {
                uint2 q[EPH];
                #pragma unroll
                for (int u = 0; u < EPH; u++)
                    q[u] = *(const uint2*)(rowbase + (size_t)s[u] * (C / 2) + coff);
                #pragma unroll
                for (int u = 0; u < EPH; u++) {
                    f32x2_t w2 = (f32x2_t){w[u], w[u]};
                    acc2[0] += w2 * b2f2(q[u].x);
                    acc2[1] += w2 * b2f2(q[u].y);
                }
            } else {
                uint q[EPH];
                #pragma unroll
                for (int u = 0; u < EPH; u++)
                    q[u] = rowbase[(size_t)s[u] * (C / 2) + coff];
                #pragma unroll
                for (int u = 0; u < EPH; u++) {
                    f32x2_t w2 = (f32x2_t){w[u], w[u]};
                    acc2[0] += w2 * b2f2(q[u]);
                }
            }
        }
        int done = full * G;
        if (done < m) {
            int   s[EPH];
            float w[EPH];
            #pragma unroll
            for (int u = 0; u < EPH; u++) {
                int e = done + 2 * u + h;
                int sv = __shfl((int)mt.x, e & 63);
                uint wu = (uint)__shfl((int)mt.y, e & 63);
                bool ok = (e < m);
                s[u] = ok ? sv : 0;
                w[u] = ok ? __uint_as_float(wu) : 0.0f;
            }
            if constexpr (UPL == 2) {
                uint2 q[EPH];
                #pragma unroll
                for (int u = 0; u < EPH; u++)
                    q[u] = *(const uint2*)(rowbase + (size_t)s[u] * (C / 2) + coff);
                #pragma unroll
                for (int u = 0; u < EPH; u++) {
                    f32x2_t w2 = (f32x2_t){w[u], w[u]};
                    acc2[0] += w2 * b2f2(q[u].x);
                    acc2[1] += w2 * b2f2(q[u].y);
                }
            } else {
                uint q[EPH];
                #pragma unroll
                for (int u = 0; u < EPH; u++)
                    q[u] = rowbase[(size_t)s[u] * (C / 2) + coff];
                #pragma unroll
                for (int u = 0; u < EPH; u++) {
                    f32x2_t w2 = (f32x2_t){w[u], w[u]};
                    acc2[0] += w2 * b2f2(q[u]);
                }
            }
        }
    }

    #pragma unroll
    for (int k = 0; k < UPL; k++) {
        acc2[k].x += __shfl_xor(acc2[k].x, 32);
        acc2[k].y += __shfl_xor(acc2[k].y, 32);
    }

    if (h == 0) {
        uint* po = (uint*)out + (size_t)i * (C / 2) + coff;
        if constexpr (UPL == 2) {
            uint2 o;
            o.x = pack2(acc2[0].x, acc2[0].y);
            o.y = pack2(acc2[1].x, acc2[1].y);
            *(uint2*)po = o;
        } else {
            *po = pack2(acc2[0].x, acc2[0].y);
        }
    }
}

// ---------------------------------------------------------------------------
// MFMA GEMM v4: LDS-staged B + software-pipelined A loads.
// block 256 = 4 waves, BM=128 (32 rows/wave), BN=128.
// A-loads for K-step k+1 issued before the MFMA block of step k, so the
// ~300-500cyc LLC latency is hidden even at 2 blocks/CU occupancy.
// ---------------------------------------------------------------------------
template<int K>
__global__ __launch_bounds__(256) void gemm_kernel(const ushort* __restrict__ A,
                                                   const ushort* __restrict__ Bt,
                                                   const float* __restrict__ bias,
                                                   ushort* __restrict__ C, int M) {
    constexpr int PITCH = K + 4;
    __shared__ ushort Bs[128 * PITCH];

    int tid = threadIdx.x;
    int wave = tid >> 6;
    int lane = tid & 63;
    int quad = lane >> 4;
    int r = lane & 15;
    int bm = blockIdx.x * 128 + wave * 32;
    int bn = blockIdx.y * 128;

    // stage B: 128 rows x K ushorts, coalesced 16B chunks
    constexpr int CPR = K / 8;
    constexpr int TOT = 128 * CPR;
    for (int idx = tid; idx < TOT; idx += 256) {
        int row = idx / CPR;
        int kc = idx % CPR;
        *(bf16x8_t*)&Bs[row * PITCH + kc * 8] =
            *(const bf16x8_t*)&Bt[(size_t)(bn + row) * K + kc * 8];
    }

    int rowA0 = bm + r;       if (rowA0 >= M) rowA0 = M - 1;
    int rowA1 = bm + 16 + r;  if (rowA1 >= M) rowA1 = M - 1;
    const ushort* pA0 = A + (size_t)rowA0 * K + quad * 8;
    const ushort* pA1 = A + (size_t)rowA1 * K + quad * 8;
    const ushort* pBs = &Bs[r * PITCH + quad * 8];

    // prefetch first A frags while B staging completes
    bf16x8_t a0 = *(const bf16x8_t*)(pA0);
    bf16x8_t a1 = *(const bf16x8_t*)(pA1);

    __syncthreads();

    f32x4_t acc[2][8];
    #pragma unroll
    for (int mt = 0; mt < 2; mt++)
        #pragma unroll
        for (int nt = 0; nt < 8; nt++)
            acc[mt][nt] = (f32x4_t){0.f, 0.f, 0.f, 0.f};

    #pragma unroll
    for (int kt = 0; kt < K; kt += 32) {
        bf16x8_t n0, n1;
        if (kt + 32 < K) {
            n0 = *(const bf16x8_t*)(pA0 + kt + 32);
            n1 = *(const bf16x8_t*)(pA1 + kt + 32);
        }
        #pragma unroll
        for (int nt = 0; nt < 8; nt++) {
            bf16x8_t b = *(const bf16x8_t*)(pBs + nt * 16 * PITCH + kt);
            acc[0][nt] = __builtin_amdgcn_mfma_f32_16x16x32_bf16(a0, b, acc[0][nt], 0, 0, 0);
            acc[1][nt] = __builtin_amdgcn_mfma_f32_16x16x32_bf16(a1, b, acc[1][nt], 0, 0, 0);
        }
        if (kt + 32 < K) { a0 = n0; a1 = n1; }
    }

    #pragma unroll
    for (int mt = 0; mt < 2; mt++) {
        #pragma unroll
        for (int i = 0; i < 4; i++) {
            int grow = bm + mt * 16 + quad * 4 + i;
            if (grow < M) {
                #pragma unroll
                for (int nt = 0; nt < 8; nt++) {
                    int gcol = bn + nt * 16 + r;
                    float v = acc[mt][nt][i] + bias[gcol];
                    v = fmaxf(v, 0.0f);
                    C[(size_t)grow * 256 + gcol] = f2b(v);
                }
            }
        }
    }
}

// ---------------------------------------------------------------------------
// Pool + head
// ---------------------------------------------------------------------------
__global__ __launch_bounds__(256) void pool_kernel(const ushort* __restrict__ H,
                                                   const int* __restrict__ bp,
                                                   float* __restrict__ pooled) {
    int g = blockIdx.x, part = blockIdx.y;
    int beg = bp[g], end = bp[g + 1];
    int cnt = end - beg;
    int per = (cnt + 7) >> 3;
    int rb = beg + part * per;
    int re = rb + per; if (re > end) re = end;
    if (rb >= re) return;
    int c = threadIdx.x;
    float acc = 0.0f;
    for (int i = rb; i < re; i++) acc += b2f(H[(size_t)i * 256 + c]);
    atomicAdd(&pooled[(size_t)g * 256 + c], acc);
}

__global__ __launch_bounds__(64) void head_kernel(const float* __restrict__ pooled,
                                                  const int* __restrict__ bp,
                                                  const float* __restrict__ Wout,
                                                  const float* __restrict__ bout,
                                                  float* __restrict__ out) {
    int g = blockIdx.x;
    int lane = threadIdx.x;
    float inv = 1.0f / fmaxf((float)(bp[g + 1] - bp[g]), 1.0f);
    const float* pg = pooled + (size_t)g * HH;
    float s[TT] = {};
    for (int c = lane; c < HH; c += 64) {
        float p = pg[c] * inv;
        #pragma unroll
        for (int t = 0; t < TT; t++) s[t] += p * Wout[c * TT + t];
    }
    #pragma unroll
    for (int t = 0; t < TT; t++) {
        float v = s[t];
        for (int off = 32; off > 0; off >>= 1) v += __shfl_down(v, off);
        if (lane == 0) out[(size_t)g * TT + t] = v + bout[t];
    }
}

// ---------------------------------------------------------------------------
// Launch
// ---------------------------------------------------------------------------
extern "C" void kernel_launch(void* const* d_in, const int* in_sizes, int n_in,
                              void* d_out, int out_size, void* d_ws, size_t ws_size,
                              hipStream_t stream) {
    const float* x     = (const float*)d_in[0];
    const int*   esrc  = (const int*)d_in[1];
    const int*   edst  = ((const int*)d_in[1]) + EE;
    const int*   batch = (const int*)d_in[2];
    const float* W0 = (const float*)d_in[3];  const float* b0 = (const float*)d_in[4];
    const float* W1 = (const float*)d_in[5];  const float* b1 = (const float*)d_in[6];
    const float* W2 = (const float*)d_in[7];  const float* b2 = (const float*)d_in[8];
    const float* W3 = (const float*)d_in[9];  const float* b3 = (const float*)d_in[10];
    const float* Wout = (const float*)d_in[11]; const float* bout = (const float*)d_in[12];
    float* out = (float*)d_out;

    char* p = (char*)d_ws;
    size_t off = 0;
    auto alloc = [&](size_t bytes) {
        void* r = p + off;
        off += (bytes + 255) & ~(size_t)255;
        return r;
    };
    int*    cnt      = (int*)alloc((size_t)NN * 4);
    int*    row_ptr  = (int*)alloc((size_t)(NN + 1) * 4);
    int*    cursor   = (int*)alloc((size_t)NN * 4);
    float*  dinv     = (float*)alloc((size_t)NN * 4);
    float*  selfnorm = (float*)alloc((size_t)NN * 4);
    int*    bsum     = (int*)alloc(256 * 4);
    int*    boff     = (int*)alloc(256 * 4);
    int*    bp       = (int*)alloc((size_t)(GG + 1) * 4);
    uint2*  meta     = (uint2*)alloc((size_t)EE * 8);
    ushort* xb       = (ushort*)alloc((size_t)NN * FF * 2);
    ushort* aggX     = (ushort*)alloc((size_t)NN * FF * 2);
    ushort* hA       = (ushort*)alloc((size_t)NN * HH * 2);
    ushort* hB       = (ushort*)alloc((size_t)NN * HH * 2);
    ushort* Wt0      = (ushort*)alloc((size_t)FF * HH * 2);
    ushort* Wt1      = (ushort*)alloc((size_t)HH * HH * 2);
    ushort* Wt2      = (ushort*)alloc((size_t)HH * HH * 2);
    ushort* Wt3      = (ushort*)alloc((size_t)HH * HH * 2);
    float*  pooled   = (float*)alloc((size_t)GG * HH * 4);
    (void)ws_size;

    const int NB = (NN + 255) / 256;

    hipMemsetAsync(cnt, 0, (size_t)NN * 4, stream);
    hipMemsetAsync(pooled, 0, (size_t)GG * HH * 4, stream);
    prep_kernel<<<CNTB + 3 + FF + 3 * HH + (NN * FF / 4 + 255) / 256, 256, 0, stream>>>(
        edst, cnt, batch, bp, W0, W1, W2, W3, Wt0, Wt1, Wt2, Wt3, x, xb);
    blocksum_kernel<<<NB, 256, 0, stream>>>(cnt, bsum, NN);
    scanb_kernel<<<1, 256, 0, stream>>>(bsum, boff, NB);
    rowptr_kernel<<<NB, 256, 0, stream>>>(cnt, boff, row_ptr, cursor, dinv, selfnorm, NN);
    scatter_kernel<<<(EE + 255) / 256, 256, 0, stream>>>(esrc, edst, row_ptr, cursor,
                                                         meta, dinv, EE);

    dim3 ggrid((NN + 127) / 128, 2);
    int aggblocks = 2 * ((NN + 3) / 4);

    agg_kernel<FF><<<aggblocks, 256, 0, stream>>>(xb, row_ptr, meta, selfnorm, aggX);
    gemm_kernel<FF><<<ggrid, 256, 0, stream>>>(aggX, Wt0, b0, hA, NN);
    agg_kernel<HH><<<aggblocks, 256, 0, stream>>>(hA, row_ptr, meta, selfnorm, hB);
    gemm_kernel<HH><<<ggrid, 256, 0, stream>>>(hB, Wt1, b1, hA, NN);
    agg_kernel<HH><<<aggblocks, 256, 0, stream>>>(hA, row_ptr, meta, selfnorm, hB);
    gemm_kernel<HH><<<ggrid, 256, 0, stream>>>(hB, Wt2, b2, hA, NN);
    agg_kernel<HH><<<aggblocks, 256, 0, stream>>>(hA, row_ptr, meta, selfnorm, hB);
    gemm_kernel<HH><<<ggrid, 256, 0, stream>>>(hB, Wt3, b3, hA, NN);

    dim3 pgrid(GG, 8);
    pool_kernel<<<pgrid, 256, 0, stream>>>(hA, bp, pooled);
    head_kernel<<<GG, 64, 0, stream>>>(pooled, bp, Wout, bout, out);
}

// Round 12
// 533.097 us; speedup vs baseline: 1.0496x; 1.0496x over previous
//
#include <hip/hip_runtime.h>
#include <hip/hip_bf16.h>

#define NN 50000
#define EE 800000
#define FF 128
#define HH 256
#define GG 512
#define TT 5

typedef __attribute__((ext_vector_type(8))) short bf16x8_t;
typedef __attribute__((ext_vector_type(4))) float f32x4_t;
typedef __attribute__((ext_vector_type(2))) float f32x2_t;

__device__ __forceinline__ ushort f2b(float f) {
    union { float f; uint u; } c; c.f = f;
    uint u = c.u;
    u += 0x7fffu + ((u >> 16) & 1u);
    return (ushort)(u >> 16);
}
__device__ __forceinline__ float b2f(ushort h) {
    union { uint u; float f; } c; c.u = ((uint)h) << 16;
    return c.f;
}
__device__ __forceinline__ f32x2_t b2f2(uint q) {
    union { uint u; float f; } lo, hi;
    lo.u = q << 16; hi.u = q & 0xffff0000u;
    return (f32x2_t){lo.f, hi.f};
}
__device__ __forceinline__ uint pack2(float a, float b) {
    return (uint)f2b(a) | ((uint)f2b(b) << 16);
}

// ---------------------------------------------------------------------------
// Preprocessing
// ---------------------------------------------------------------------------
__global__ __launch_bounds__(256) void blocksum_kernel(const int* __restrict__ cnt,
                                                       int* __restrict__ bsum, int n) {
    __shared__ int sm[256];
    int i = blockIdx.x * 256 + threadIdx.x;
    sm[threadIdx.x] = (i < n) ? cnt[i] : 0;
    __syncthreads();
    for (int s = 128; s > 0; s >>= 1) {
        if ((int)threadIdx.x < s) sm[threadIdx.x] += sm[threadIdx.x + s];
        __syncthreads();
    }
    if (threadIdx.x == 0) bsum[blockIdx.x] = sm[0];
}

__global__ __launch_bounds__(256) void scanb_kernel(const int* __restrict__ bsum,
                                                    int* __restrict__ boff, int nb) {
    __shared__ int sm[256];
    int v = ((int)threadIdx.x < nb) ? bsum[threadIdx.x] : 0;
    sm[threadIdx.x] = v;
    __syncthreads();
    for (int off = 1; off < 256; off <<= 1) {
        int t = (threadIdx.x >= (unsigned)off) ? sm[threadIdx.x - off] : 0;
        __syncthreads();
        sm[threadIdx.x] += t;
        __syncthreads();
    }
    if ((int)threadIdx.x < nb) boff[threadIdx.x] = sm[threadIdx.x] - v;
}

__global__ __launch_bounds__(256) void rowptr_kernel(const int* __restrict__ cnt,
                                                     const int* __restrict__ boff,
                                                     int* __restrict__ row_ptr,
                                                     int* __restrict__ cursor,
                                                     float* __restrict__ dinv,
                                                     float* __restrict__ selfnorm, int n) {
    __shared__ int sm[256];
    int i = blockIdx.x * 256 + threadIdx.x;
    int v = (i < n) ? cnt[i] : 0;
    sm[threadIdx.x] = v;
    __syncthreads();
    for (int off = 1; off < 256; off <<= 1) {
        int t = (threadIdx.x >= (unsigned)off) ? sm[threadIdx.x - off] : 0;
        __syncthreads();
        sm[threadIdx.x] += t;
        __syncthreads();
    }
    int excl = boff[blockIdx.x] + sm[threadIdx.x] - v;
    if (i < n) {
        row_ptr[i] = excl;
        cursor[i] = 0;
        float dv = 1.0f / sqrtf((float)(v + 1));
        dinv[i] = dv;
        selfnorm[i] = dv * dv;
    }
    if (i == n - 1) row_ptr[n] = excl + v;
}

__global__ void scatter_kernel(const int* __restrict__ src, const int* __restrict__ dst,
                               const int* __restrict__ row_ptr, int* __restrict__ cursor,
                               uint2* __restrict__ meta,
                               const float* __restrict__ dinv, int e) {
    int t = blockIdx.x * blockDim.x + threadIdx.x;
    if (t >= e) return;
    int s = src[t], d = dst[t];
    int pos = row_ptr[d] + atomicAdd(&cursor[d], 1);
    uint2 m;
    m.x = (uint)s;
    m.y = __float_as_uint(dinv[s] * dinv[d]);
    meta[pos] = m;
}

// Fused: count | bp | wt casts | cvtx  (all independent; atomics into cnt)
#define CNTB ((EE + 255) / 256)
__global__ __launch_bounds__(256) void prep_kernel(const int* __restrict__ edst,
                                                   int* __restrict__ cnt,
                                                   const int* __restrict__ batch,
                                                   int* __restrict__ bp,
                                                   const float* __restrict__ W0,
                                                   const float* __restrict__ W1,
                                                   const float* __restrict__ W2,
                                                   const float* __restrict__ W3,
                                                   ushort* __restrict__ Wt0,
                                                   ushort* __restrict__ Wt1,
                                                   ushort* __restrict__ Wt2,
                                                   ushort* __restrict__ Wt3,
                                                   const float* __restrict__ x,
                                                   ushort* __restrict__ xb) {
    int b = blockIdx.x;
    if (b < CNTB) {
        int t = b * 256 + threadIdx.x;
        if (t < EE) atomicAdd(&cnt[edst[t]], 1);
    } else if (b < CNTB + 3) {
        int t = (b - CNTB) * 256 + threadIdx.x;
        if (t > GG) return;
        int lo = 0, hi = NN;
        while (lo < hi) {
            int mid = (lo + hi) >> 1;
            if (batch[mid] < t) lo = mid + 1; else hi = mid;
        }
        bp[t] = lo;
    } else if (b < CNTB + 3 + FF + 3 * HH) {
        int wb = b - CNTB - 3;
        const float* W; ushort* Wt; int K, kb;
        if (wb < FF)             { W = W0; Wt = Wt0; K = FF; kb = wb; }
        else if (wb < FF + HH)   { W = W1; Wt = Wt1; K = HH; kb = wb - FF; }
        else if (wb < FF + 2*HH) { W = W2; Wt = Wt2; K = HH; kb = wb - FF - HH; }
        else                     { W = W3; Wt = Wt3; K = HH; kb = wb - FF - 2*HH; }
        int n = threadIdx.x;
        Wt[(size_t)n * K + kb] = f2b(W[(size_t)kb * 256 + n]);
    } else {
        int i = (b - CNTB - 3 - FF - 3 * HH) * 256 + threadIdx.x;
        if (i >= NN * FF / 4) return;
        float4 v = ((const float4*)x)[i];
        ushort4 o;
        o.x = f2b(v.x); o.y = f2b(v.y); o.z = f2b(v.z); o.w = f2b(v.w);
        ((ushort4*)xb)[i] = o;
    }
}

// ---------------------------------------------------------------------------
// Aggregation v6 (unchanged — at structural floor: per-XCD misses ~= compulsory)
// ---------------------------------------------------------------------------
template<int C>
__global__ __launch_bounds__(256) void agg_kernel(const ushort* __restrict__ H,
                                                  const int* __restrict__ row_ptr,
                                                  const uint2* __restrict__ meta,
                                                  const float* __restrict__ selfnorm,
                                                  ushort* __restrict__ out) {
    constexpr int UPL = C / 128;
    constexpr int EPH = 8;
    constexpr int G   = 2 * EPH;
    int wave = threadIdx.x >> 6;
    int lane = threadIdx.x & 63;
    int h = lane >> 5;
    int cl = lane & 31;
    int colhalf = blockIdx.x & 1;
    int i = (blockIdx.x >> 1) * 4 + wave;
    if (i >= NN) return;

    const int coff = colhalf * (C / 4) + cl * UPL;

    f32x2_t acc2[UPL];
    #pragma unroll
    for (int k = 0; k < UPL; k++) acc2[k] = (f32x2_t){0.f, 0.f};

    const uint* rowbase = (const uint*)H;
    if (h == 0) {
        float sn = selfnorm[i];
        const uint* p = rowbase + (size_t)i * (C / 2) + coff;
        #pragma unroll
        for (int u = 0; u < UPL; u++) {
            f32x2_t v = b2f2(p[u]);
            acc2[u].x = sn * v.x;
            acc2[u].y = sn * v.y;
        }
    }

    int beg = row_ptr[i], end = row_ptr[i + 1];
    for (int base = beg; base < end; base += 64) {
        int t = base + lane;
        uint2 mt;
        if (t < end) mt = meta[t]; else { mt.x = 0u; mt.y = 0u; }
        int m = end - base; if (m > 64) m = 64;
        int full = m / G;
        for (int jj = 0; jj < full; jj++) {
            int   s[EPH];
            float w[EPH];
            #pragma unroll
            for (int u = 0; u < EPH; u++) {
                int e = G * jj + 2 * u + h;
                s[u] = __shfl((int)mt.x, e);
                w[u] = __uint_as_float((uint)__shfl((int)mt.y, e));
            }
            if constexpr (UPL == 2) {
                uint2 q[EPH];
                #pragma unroll
                for (int u = 0; u < EPH; u++)
                    q[u] = *(const uint2*)(rowbase + (size_t)s[u] * (C / 2) + coff);
                #pragma unroll
                for (int u = 0; u < EPH; u++) {
                    f32x2_t w2 = (f32x2_t){w[u], w[u]};
                    acc2[0] += w2 * b2f2(q[u].x);
                    acc2[1] += w2 * b2f2(q[u].y);
                }
            } else {
                uint q[EPH];
                #pragma unroll
                for (int u = 0; u < EPH; u++)
                    q[u] = rowbase[(size_t)s[u] * (C / 2) + coff];
                #pragma unroll
                for (int u = 0; u < EPH; u++) {
                    f32x2_t w2 = (f32x2_t){w[u], w[u]};
                    acc2[0] += w2 * b2f2(q[u]);
                }
            }
        }
        int done = full * G;
        if (done < m) {
            int   s[EPH];
            float w[EPH];
            #pragma unroll
            for (int u = 0; u < EPH; u++) {
                int e = done + 2 * u + h;
                int sv = __shfl((int)mt.x, e & 63);
                uint wu = (uint)__shfl((int)mt.y, e & 63);
                bool ok = (e < m);
                s[u] = ok ? sv : 0;
                w[u] = ok ? __uint_as_float(wu) : 0.0f;
            }
            if constexpr (UPL == 2) {
                uint2 q[EPH];
                #pragma unroll
                for (int u = 0; u < EPH; u++)
                    q[u] = *(const uint2*)(rowbase + (size_t)s[u] * (C / 2) + coff);
                #pragma unroll
                for (int u = 0; u < EPH; u++) {
                    f32x2_t w2 = (f32x2_t){w[u], w[u]};
                    acc2[0] += w2 * b2f2(q[u].x);
                    acc2[1] += w2 * b2f2(q[u].y);
                }
            } else {
                uint q[EPH];
                #pragma unroll
                for (int u = 0; u < EPH; u++)
                    q[u] = rowbase[(size_t)s[u] * (C / 2) + coff];
                #pragma unroll
                for (int u = 0; u < EPH; u++) {
                    f32x2_t w2 = (f32x2_t){w[u], w[u]};
                    acc2[0] += w2 * b2f2(q[u]);
                }
            }
        }
    }

    #pragma unroll
    for (int k = 0; k < UPL; k++) {
        acc2[k].x += __shfl_xor(acc2[k].x, 32);
        acc2[k].y += __shfl_xor(acc2[k].y, 32);
    }

    if (h == 0) {
        uint* po = (uint*)out + (size_t)i * (C / 2) + coff;
        if constexpr (UPL == 2) {
            uint2 o;
            o.x = pack2(acc2[0].x, acc2[0].y);
            o.y = pack2(acc2[1].x, acc2[1].y);
            *(uint2*)po = o;
        } else {
            *po = pack2(acc2[0].x, acc2[0].y);
        }
    }
}

// ---------------------------------------------------------------------------
// MFMA GEMM v5: split-K LDS staging. block 256 = 4 waves, BM=128, BN=128.
// B staged in K=128 half-stages -> LDS 33.8 KB -> 4 blocks/CU (16 waves/CU),
// double the occupancy of the single-stage version at same traffic.
// ---------------------------------------------------------------------------
template<int K>
__global__ __launch_bounds__(256) void gemm_kernel(const ushort* __restrict__ A,
                                                   const ushort* __restrict__ Bt,
                                                   const float* __restrict__ bias,
                                                   ushort* __restrict__ C, int M) {
    constexpr int KS = 128;            // k per stage
    constexpr int PITCH = KS + 4;      // 132 ushorts
    __shared__ ushort Bs[128 * PITCH]; // 33792 B

    int tid = threadIdx.x;
    int wave = tid >> 6;
    int lane = tid & 63;
    int quad = lane >> 4;
    int r = lane & 15;
    int bm = blockIdx.x * 128 + wave * 32;
    int bn = blockIdx.y * 128;

    int rowA0 = bm + r;       if (rowA0 >= M) rowA0 = M - 1;
    int rowA1 = bm + 16 + r;  if (rowA1 >= M) rowA1 = M - 1;
    const ushort* pA0 = A + (size_t)rowA0 * K + quad * 8;
    const ushort* pA1 = A + (size_t)rowA1 * K + quad * 8;

    f32x4_t acc[2][8];
    #pragma unroll
    for (int mt = 0; mt < 2; mt++)
        #pragma unroll
        for (int nt = 0; nt < 8; nt++)
            acc[mt][nt] = (f32x4_t){0.f, 0.f, 0.f, 0.f};

    const ushort* pBs = &Bs[r * PITCH + quad * 8];

    #pragma unroll
    for (int ks = 0; ks < K; ks += KS) {
        if (ks) __syncthreads();   // protect Bs from overwrite while in use
        // stage Bt[:, ks:ks+128]: 128 rows x 16 chunks of 16B, coalesced
        #pragma unroll
        for (int it = 0; it < 8; it++) {
            int idx = it * 256 + tid;
            int row = idx >> 4;
            int kc = idx & 15;
            *(bf16x8_t*)&Bs[row * PITCH + kc * 8] =
                *(const bf16x8_t*)&Bt[(size_t)(bn + row) * K + ks + kc * 8];
        }
        __syncthreads();
        #pragma unroll
        for (int kt = 0; kt < KS; kt += 32) {
            bf16x8_t a0 = *(const bf16x8_t*)(pA0 + ks + kt);
            bf16x8_t a1 = *(const bf16x8_t*)(pA1 + ks + kt);
            #pragma unroll
            for (int nt = 0; nt < 8; nt++) {
                bf16x8_t b = *(const bf16x8_t*)(pBs + nt * 16 * PITCH + kt);
                acc[0][nt] = __builtin_amdgcn_mfma_f32_16x16x32_bf16(a0, b, acc[0][nt], 0, 0, 0);
                acc[1][nt] = __builtin_amdgcn_mfma_f32_16x16x32_bf16(a1, b, acc[1][nt], 0, 0, 0);
            }
        }
    }

    #pragma unroll
    for (int mt = 0; mt < 2; mt++) {
        #pragma unroll
        for (int i = 0; i < 4; i++) {
            int grow = bm + mt * 16 + quad * 4 + i;
            if (grow < M) {
                #pragma unroll
                for (int nt = 0; nt < 8; nt++) {
                    int gcol = bn + nt * 16 + r;
                    float v = acc[mt][nt][i] + bias[gcol];
                    v = fmaxf(v, 0.0f);
                    C[(size_t)grow * 256 + gcol] = f2b(v);
                }
            }
        }
    }
}

// ---------------------------------------------------------------------------
// Pool + head
// ---------------------------------------------------------------------------
__global__ __launch_bounds__(256) void pool_kernel(const ushort* __restrict__ H,
                                                   const int* __restrict__ bp,
                                                   float* __restrict__ pooled) {
    int g = blockIdx.x, part = blockIdx.y;
    int beg = bp[g], end = bp[g + 1];
    int cnt = end - beg;
    int per = (cnt + 7) >> 3;
    int rb = beg + part * per;
    int re = rb + per; if (re > end) re = end;
    if (rb >= re) return;
    int c = threadIdx.x;
    float acc = 0.0f;
    for (int i = rb; i < re; i++) acc += b2f(H[(size_t)i * 256 + c]);
    atomicAdd(&pooled[(size_t)g * 256 + c], acc);
}

__global__ __launch_bounds__(64) void head_kernel(const float* __restrict__ pooled,
                                                  const int* __restrict__ bp,
                                                  const float* __restrict__ Wout,
                                                  const float* __restrict__ bout,
                                                  float* __restrict__ out) {
    int g = blockIdx.x;
    int lane = threadIdx.x;
    float inv = 1.0f / fmaxf((float)(bp[g + 1] - bp[g]), 1.0f);
    const float* pg = pooled + (size_t)g * HH;
    float s[TT] = {};
    for (int c = lane; c < HH; c += 64) {
        float p = pg[c] * inv;
        #pragma unroll
        for (int t = 0; t < TT; t++) s[t] += p * Wout[c * TT + t];
    }
    #pragma unroll
    for (int t = 0; t < TT; t++) {
        float v = s[t];
        for (int off = 32; off > 0; off >>= 1) v += __shfl_down(v, off);
        if (lane == 0) out[(size_t)g * TT + t] = v + bout[t];
    }
}

// ---------------------------------------------------------------------------
// Launch
// ---------------------------------------------------------------------------
extern "C" void kernel_launch(void* const* d_in, const int* in_sizes, int n_in,
                              void* d_out, int out_size, void* d_ws, size_t ws_size,
                              hipStream_t stream) {
    const float* x     = (const float*)d_in[0];
    const int*   esrc  = (const int*)d_in[1];
    const int*   edst  = ((const int*)d_in[1]) + EE;
    const int*   batch = (const int*)d_in[2];
    const float* W0 = (const float*)d_in[3];  const float* b0 = (const float*)d_in[4];
    const float* W1 = (const float*)d_in[5];  const float* b1 = (const float*)d_in[6];
    const float* W2 = (const float*)d_in[7];  const float* b2 = (const float*)d_in[8];
    const float* W3 = (const float*)d_in[9];  const float* b3 = (const float*)d_in[10];
    const float* Wout = (const float*)d_in[11]; const float* bout = (const float*)d_in[12];
    float* out = (float*)d_out;

    char* p = (char*)d_ws;
    size_t off = 0;
    auto alloc = [&](size_t bytes) {
        void* r = p + off;
        off += (bytes + 255) & ~(size_t)255;
        return r;
    };
    int*    cnt      = (int*)alloc((size_t)NN * 4);
    int*    row_ptr  = (int*)alloc((size_t)(NN + 1) * 4);
    int*    cursor   = (int*)alloc((size_t)NN * 4);
    float*  dinv     = (float*)alloc((size_t)NN * 4);
    float*  selfnorm = (float*)alloc((size_t)NN * 4);
    int*    bsum     = (int*)alloc(256 * 4);
    int*    boff     = (int*)alloc(256 * 4);
    int*    bp       = (int*)alloc((size_t)(GG + 1) * 4);
    uint2*  meta     = (uint2*)alloc((size_t)EE * 8);
    ushort* xb       = (ushort*)alloc((size_t)NN * FF * 2);
    ushort* aggX     = (ushort*)alloc((size_t)NN * FF * 2);
    ushort* hA       = (ushort*)alloc((size_t)NN * HH * 2);
    ushort* hB       = (ushort*)alloc((size_t)NN * HH * 2);
    ushort* Wt0      = (ushort*)alloc((size_t)FF * HH * 2);
    ushort* Wt1      = (ushort*)alloc((size_t)HH * HH * 2);
    ushort* Wt2      = (ushort*)alloc((size_t)HH * HH * 2);
    ushort* Wt3      = (ushort*)alloc((size_t)HH * HH * 2);
    float*  pooled   = (float*)alloc((size_t)GG * HH * 4);
    (void)ws_size;

    const int NB = (NN + 255) / 256;

    hipMemsetAsync(cnt, 0, (size_t)NN * 4, stream);
    hipMemsetAsync(pooled, 0, (size_t)GG * HH * 4, stream);
    prep_kernel<<<CNTB + 3 + FF + 3 * HH + (NN * FF / 4 + 255) / 256, 256, 0, stream>>>(
        edst, cnt, batch, bp, W0, W1, W2, W3, Wt0, Wt1, Wt2, Wt3, x, xb);
    blocksum_kernel<<<NB, 256, 0, stream>>>(cnt, bsum, NN);
    scanb_kernel<<<1, 256, 0, stream>>>(bsum, boff, NB);
    rowptr_kernel<<<NB, 256, 0, stream>>>(cnt, boff, row_ptr, cursor, dinv, selfnorm, NN);
    scatter_kernel<<<(EE + 255) / 256, 256, 0, stream>>>(esrc, edst, row_ptr, cursor,
                                                         meta, dinv, EE);

    dim3 ggrid((NN + 127) / 128, 2);
    int aggblocks = 2 * ((NN + 3) / 4);

    agg_kernel<FF><<<aggblocks, 256, 0, stream>>>(xb, row_ptr, meta, selfnorm, aggX);
    gemm_kernel<FF><<<ggrid, 256, 0, stream>>>(aggX, Wt0, b0, hA, NN);
    agg_kernel<HH><<<aggblocks, 256, 0, stream>>>(hA, row_ptr, meta, selfnorm, hB);
    gemm_kernel<HH><<<ggrid, 256, 0, stream>>>(hB, Wt1, b1, hA, NN);
    agg_kernel<HH><<<aggblocks, 256, 0, stream>>>(hA, row_ptr, meta, selfnorm, hB);
    gemm_kernel<HH><<<ggrid, 256, 0, stream>>>(hB, Wt2, b2, hA, NN);
    agg_kernel<HH><<<aggblocks, 256, 0, stream>>>(hA, row_ptr, meta, selfnorm, hB);
    gemm_kernel<HH><<<ggrid, 256, 0, stream>>>(hB, Wt3, b3, hA, NN);

    dim3 pgrid(GG, 8);
    pool_kernel<<<pgrid, 256, 0, stream>>>(hA, bp, pooled);
    head_kernel<<<GG, 64, 0, stream>>>(pooled, bp, Wout, bout, out);
}